// Round 1
// baseline (102.948 us; speedup 1.0000x reference)
//
#include <hip/hip_runtime.h>
#include <hip/hip_bf16.h>

#define BATCH 8
#define NPT   2048
#define DIM   512

typedef __attribute__((ext_vector_type(8))) short bf16x8;
typedef __attribute__((ext_vector_type(4))) float f32x4;

// ---------------- workspace layout ----------------
// xn       : bf16 [BATCH*NPT*DIM]   offset 0            16,777,216 B
// sq       : f32  [BATCH*NPT]       offset 16,777,216       65,536 B
// msum     : f32  [BATCH]           offset 16,842,752           32 B
// partials : f32  [2048]            offset 16,842,784        8,192 B
#define OFF_SQ       16777216
#define OFF_MSUM     16842752
#define OFF_PARTIALS 16842784

// ---------------- kernel 1: normalize rows, emit bf16 + per-row |x|^2 ----------------
__global__ __launch_bounds__(256) void normalize_kernel(const float* __restrict__ emb,
                                                        __hip_bfloat16* __restrict__ xn,
                                                        float* __restrict__ sq) {
    const int wave = threadIdx.x >> 6;
    const int lane = threadIdx.x & 63;
    const int row  = blockIdx.x * 4 + wave;           // [0, BATCH*NPT)

    const float4* src = (const float4*)(emb + (size_t)row * DIM);
    float4 v0 = src[lane * 2 + 0];
    float4 v1 = src[lane * 2 + 1];

    float ss = v0.x*v0.x + v0.y*v0.y + v0.z*v0.z + v0.w*v0.w
             + v1.x*v1.x + v1.y*v1.y + v1.z*v1.z + v1.w*v1.w;
#pragma unroll
    for (int o = 32; o; o >>= 1) ss += __shfl_xor(ss, o);

    const float inv = 1.0f / fmaxf(sqrtf(ss), 1e-12f);

    float vals[8] = {v0.x, v0.y, v0.z, v0.w, v1.x, v1.y, v1.z, v1.w};
    unsigned int w[4];
    float s2 = 0.f;
#pragma unroll
    for (int i = 0; i < 4; i++) {
        __hip_bfloat16 h0 = __float2bfloat16(vals[2*i]   * inv);
        __hip_bfloat16 h1 = __float2bfloat16(vals[2*i+1] * inv);
        unsigned short u0 = *(unsigned short*)&h0;
        unsigned short u1 = *(unsigned short*)&h1;
        w[i] = (unsigned int)u0 | ((unsigned int)u1 << 16);
        float f0 = __bfloat162float(h0), f1 = __bfloat162float(h1);
        s2 += f0*f0 + f1*f1;
    }
    uint4 pk = {w[0], w[1], w[2], w[3]};
    *(uint4*)(xn + (size_t)row * DIM + lane * 8) = pk;

#pragma unroll
    for (int o = 32; o; o >>= 1) s2 += __shfl_xor(s2, o);
    if (lane == 0) sq[row] = s2;
}

// ---------------- kernel 2: per-batch mask sums ----------------
__global__ __launch_bounds__(256) void masksum_kernel(const float* __restrict__ mask,
                                                      float* __restrict__ msum) {
    const int b = blockIdx.x;
    float s = 0.f;
    for (int i = threadIdx.x; i < NPT; i += 256) s += mask[b * NPT + i];
#pragma unroll
    for (int o = 32; o; o >>= 1) s += __shfl_xor(s, o);
    __shared__ float ws[4];
    if ((threadIdx.x & 63) == 0) ws[threadIdx.x >> 6] = s;
    __syncthreads();
    if (threadIdx.x == 0) msum[b] = ws[0] + ws[1] + ws[2] + ws[3];
}

// ---------------- kernel 3: tiled Gram + fused loss epilogue ----------------
// 128x128 C-tile, BK=32, 4 waves (2x2), mfma_f32_16x16x32_bf16.
__global__ __launch_bounds__(256) void gram_loss_kernel(const __hip_bfloat16* __restrict__ xn,
                                                        const float* __restrict__ sq,
                                                        const float* __restrict__ coords,
                                                        const float* __restrict__ mask,
                                                        float* __restrict__ partials) {
    __shared__ __align__(16) __hip_bfloat16 lds_a[128 * 32];
    __shared__ __align__(16) __hip_bfloat16 lds_b[128 * 32];
    __shared__ float s_sqr[128], s_sqc[128], s_mr[128], s_mc[128];
    __shared__ float s_cr[128][3], s_cc[128][3];
    __shared__ float s_wsum[4];

    const int tn = blockIdx.x, tm = blockIdx.y, b = blockIdx.z;
    const int t    = threadIdx.x;
    const int wave = t >> 6, lane = t & 63;
    const int wr = wave >> 1, wc = wave & 1;
    const int lhi = lane >> 4, llo = lane & 15;

    const size_t rowBaseA = (size_t)(b * NPT + tm * 128);
    const size_t rowBaseB = (size_t)(b * NPT + tn * 128);

    f32x4 acc[4][4];
#pragma unroll
    for (int i = 0; i < 4; i++)
#pragma unroll
        for (int j = 0; j < 4; j++) acc[i][j] = (f32x4){0.f, 0.f, 0.f, 0.f};

    // staging geometry: tile = 128 rows x 32 cols bf16 = 8192 B = 8 segments of 1024 B.
    // wave w issues segments {2w, 2w+1}; lane covers elements seg*512 + lane*8 .. +7
    const int seg_row = lane >> 2;        // 0..15 within segment
    const int seg_col = (lane & 3) * 8;   // 0,8,16,24

    for (int kk = 0; kk < DIM / 32; kk++) {
        const int k0 = kk * 32;
#pragma unroll
        for (int p = 0; p < 2; p++) {
            const int s   = wave * 2 + p;
            const int row = s * 16 + seg_row;
            const __hip_bfloat16* ga = xn + (rowBaseA + row) * DIM + k0 + seg_col;
            const __hip_bfloat16* gb = xn + (rowBaseB + row) * DIM + k0 + seg_col;
            __builtin_amdgcn_global_load_lds((const __attribute__((address_space(1))) void*)ga,
                                             (__attribute__((address_space(3))) void*)(lds_a + s * 512),
                                             16, 0, 0);
            __builtin_amdgcn_global_load_lds((const __attribute__((address_space(1))) void*)gb,
                                             (__attribute__((address_space(3))) void*)(lds_b + s * 512),
                                             16, 0, 0);
        }
        __syncthreads();

        bf16x8 af[4], bfr[4];
#pragma unroll
        for (int mi = 0; mi < 4; mi++) {
            af[mi]  = *(const bf16x8*)(lds_a + (wr * 64 + mi * 16 + llo) * 32 + lhi * 8);
            bfr[mi] = *(const bf16x8*)(lds_b + (wc * 64 + mi * 16 + llo) * 32 + lhi * 8);
        }
#pragma unroll
        for (int mi = 0; mi < 4; mi++)
#pragma unroll
            for (int ni = 0; ni < 4; ni++)
                acc[mi][ni] = __builtin_amdgcn_mfma_f32_16x16x32_bf16(af[mi], bfr[ni], acc[mi][ni], 0, 0, 0);
        __syncthreads();
    }

    // stage per-row/col metadata for the epilogue
    if (t < 128) {
        const int gi = b * NPT + tm * 128 + t;
        s_sqr[t]   = sq[gi];
        s_mr[t]    = mask[gi];
        s_cr[t][0] = coords[(size_t)gi * 3 + 0];
        s_cr[t][1] = coords[(size_t)gi * 3 + 1];
        s_cr[t][2] = coords[(size_t)gi * 3 + 2];
    } else {
        const int r  = t - 128;
        const int gi = b * NPT + tn * 128 + r;
        s_sqc[r]   = sq[gi];
        s_mc[r]    = mask[gi];
        s_cc[r][0] = coords[(size_t)gi * 3 + 0];
        s_cc[r][1] = coords[(size_t)gi * 3 + 1];
        s_cc[r][2] = coords[(size_t)gi * 3 + 2];
    }
    __syncthreads();

    // C/D layout (m89/m91 verified): col = lane&15, row = (lane>>4)*4 + reg
    float lsum = 0.f;
#pragma unroll
    for (int mi = 0; mi < 4; mi++) {
#pragma unroll
        for (int j = 0; j < 4; j++) {
            const int rl  = wr * 64 + mi * 16 + lhi * 4 + j;
            const float sqr = s_sqr[rl];
            const float mr  = s_mr[rl];
            const float cx = s_cr[rl][0], cy = s_cr[rl][1], cz = s_cr[rl][2];
#pragma unroll
            for (int ni = 0; ni < 4; ni++) {
                const int cl = wc * 64 + ni * 16 + llo;
                const float g  = acc[mi][ni][j];
                float d2 = sqr + s_sqc[cl] - 2.f * g;
                d2 = fmaxf(d2, 0.f);
                const float de = sqrtf(d2);
                const float lo = fmaxf(de - 1.0f, 0.f);
                const float dx = cx - s_cc[cl][0];
                const float dy = cy - s_cc[cl][1];
                const float dz = cz - s_cc[cl][2];
                const float cd2 = dx*dx + dy*dy + dz*dz;
                const float wgt = (cd2 < 100.0f) ? mr * s_mc[cl] : 0.f;
                lsum += lo * wgt;
            }
        }
    }
#pragma unroll
    for (int o = 32; o; o >>= 1) lsum += __shfl_xor(lsum, o);
    if (lane == 0) s_wsum[wave] = lsum;
    __syncthreads();
    if (t == 0) {
        partials[(b * 16 + tm) * 16 + tn] = s_wsum[0] + s_wsum[1] + s_wsum[2] + s_wsum[3];
    }
}

// ---------------- kernel 4: final deterministic reduce ----------------
__global__ __launch_bounds__(256) void finalize_kernel(const float* __restrict__ partials,
                                                       const float* __restrict__ msum,
                                                       float* __restrict__ out) {
    double s = 0.0;
    for (int i = threadIdx.x; i < 2048; i += 256) s += (double)partials[i];
#pragma unroll
    for (int o = 32; o; o >>= 1) s += __shfl_xor(s, o);
    __shared__ double ws[4];
    if ((threadIdx.x & 63) == 0) ws[threadIdx.x >> 6] = s;
    __syncthreads();
    if (threadIdx.x == 0) {
        const double tot = ws[0] + ws[1] + ws[2] + ws[3];
        double valid = 0.0;
        for (int b = 0; b < BATCH; b++) valid += (double)msum[b] * (double)msum[b];
        out[0] = (float)(tot / (valid + 1e-8));
    }
}

extern "C" void kernel_launch(void* const* d_in, const int* in_sizes, int n_in,
                              void* d_out, int out_size, void* d_ws, size_t ws_size,
                              hipStream_t stream) {
    const float* emb    = (const float*)d_in[0];
    const float* coords = (const float*)d_in[1];
    const float* mask   = (const float*)d_in[2];

    char* ws = (char*)d_ws;
    __hip_bfloat16* xn = (__hip_bfloat16*)ws;
    float* sq          = (float*)(ws + OFF_SQ);
    float* msum        = (float*)(ws + OFF_MSUM);
    float* partials    = (float*)(ws + OFF_PARTIALS);
    float* out         = (float*)d_out;

    normalize_kernel<<<dim3(BATCH * NPT / 4), dim3(256), 0, stream>>>(emb, xn, sq);
    masksum_kernel<<<dim3(BATCH), dim3(256), 0, stream>>>(mask, msum);
    gram_loss_kernel<<<dim3(16, 16, BATCH), dim3(256), 0, stream>>>(xn, sq, coords, mask, partials);
    finalize_kernel<<<dim3(1), dim3(256), 0, stream>>>(partials, msum, out);
}

// Round 2
// 80.748 us; speedup vs baseline: 1.2749x; 1.2749x over previous
//
#include <hip/hip_runtime.h>
#include <hip/hip_bf16.h>

#define BATCH 8
#define NPT   2048
#define DIM   512
#define NTILE 16            // 2048/128 tiles per dim
#define NTRI  136           // NTILE*(NTILE+1)/2 symmetric tiles

typedef __attribute__((ext_vector_type(8))) short bf16x8;
typedef __attribute__((ext_vector_type(4))) float f32x4;

// ---------------- workspace layout ----------------
#define OFF_SQ       16777216
#define OFF_MSUM     16842752
#define OFF_PARTIALS 16842784   // 8*136 = 1088 floats

// ---------------- kernel 1: normalize rows, emit bf16 + per-row |x|^2 ----------------
__global__ __launch_bounds__(256) void normalize_kernel(const float* __restrict__ emb,
                                                        __hip_bfloat16* __restrict__ xn,
                                                        float* __restrict__ sq) {
    const int wave = threadIdx.x >> 6;
    const int lane = threadIdx.x & 63;
    const int row  = blockIdx.x * 4 + wave;

    const float4* src = (const float4*)(emb + (size_t)row * DIM);
    float4 v0 = src[lane * 2 + 0];
    float4 v1 = src[lane * 2 + 1];

    float ss = v0.x*v0.x + v0.y*v0.y + v0.z*v0.z + v0.w*v0.w
             + v1.x*v1.x + v1.y*v1.y + v1.z*v1.z + v1.w*v1.w;
#pragma unroll
    for (int o = 32; o; o >>= 1) ss += __shfl_xor(ss, o);

    const float inv = 1.0f / fmaxf(sqrtf(ss), 1e-12f);

    float vals[8] = {v0.x, v0.y, v0.z, v0.w, v1.x, v1.y, v1.z, v1.w};
    unsigned int w[4];
    float s2 = 0.f;
#pragma unroll
    for (int i = 0; i < 4; i++) {
        __hip_bfloat16 h0 = __float2bfloat16(vals[2*i]   * inv);
        __hip_bfloat16 h1 = __float2bfloat16(vals[2*i+1] * inv);
        unsigned short u0 = *(unsigned short*)&h0;
        unsigned short u1 = *(unsigned short*)&h1;
        w[i] = (unsigned int)u0 | ((unsigned int)u1 << 16);
        float f0 = __bfloat162float(h0), f1 = __bfloat162float(h1);
        s2 += f0*f0 + f1*f1;
    }
    uint4 pk = {w[0], w[1], w[2], w[3]};
    *(uint4*)(xn + (size_t)row * DIM + lane * 8) = pk;

#pragma unroll
    for (int o = 32; o; o >>= 1) s2 += __shfl_xor(s2, o);
    if (lane == 0) sq[row] = s2;
}

// ---------------- kernel 2: per-batch mask sums ----------------
__global__ __launch_bounds__(256) void masksum_kernel(const float* __restrict__ mask,
                                                      float* __restrict__ msum) {
    const int b = blockIdx.x;
    float s = 0.f;
    for (int i = threadIdx.x; i < NPT; i += 256) s += mask[b * NPT + i];
#pragma unroll
    for (int o = 32; o; o >>= 1) s += __shfl_xor(s, o);
    __shared__ float ws[4];
    if ((threadIdx.x & 63) == 0) ws[threadIdx.x >> 6] = s;
    __syncthreads();
    if (threadIdx.x == 0) msum[b] = ws[0] + ws[1] + ws[2] + ws[3];
}

// ---------------- kernel 3: symmetric tiled Gram + fused loss, 2-phase dbuf ----------------
// 128x128 C-tile, BK=32, 4 waves (2x2), mfma_f32_16x16x32_bf16.
// LDS XOR-swizzle (rule #21): linear global_load_lds dest + pre-swizzled global
// source column + swizzled ds_read address. Per 16-lane lhi-group the read is a
// bijection onto a 1024B row-block -> conflict-free.
__global__ __launch_bounds__(256) void gram_loss_kernel(const __hip_bfloat16* __restrict__ xn,
                                                        const float* __restrict__ sq,
                                                        const float* __restrict__ coords,
                                                        const float* __restrict__ mask,
                                                        float* __restrict__ partials) {
    __shared__ __align__(16) __hip_bfloat16 lds_a[2][128 * 32];
    __shared__ __align__(16) __hip_bfloat16 lds_b[2][128 * 32];
    __shared__ float s_sqr[128], s_sqc[128], s_mr[128], s_mc[128];
    __shared__ float s_cr[128][3], s_cc[128][3];
    __shared__ float s_wsum[4];

    // triangular tile decode: blockIdx.x in [0, NTRI) -> (tm, tn), tm <= tn
    int tm = 0, rem = blockIdx.x;
    while (rem >= NTILE - tm) { rem -= NTILE - tm; tm++; }
    const int tn = tm + rem;
    const int b  = blockIdx.z;

    const int t    = threadIdx.x;
    const int wave = t >> 6, lane = t & 63;
    const int wr = wave >> 1, wc = wave & 1;
    const int lhi = lane >> 4, llo = lane & 15;

    const size_t rowBaseA = (size_t)(b * NPT + tm * 128);
    const size_t rowBaseB = (size_t)(b * NPT + tn * 128);

    f32x4 acc[4][4];
#pragma unroll
    for (int i = 0; i < 4; i++)
#pragma unroll
        for (int j = 0; j < 4; j++) acc[i][j] = (f32x4){0.f, 0.f, 0.f, 0.f};

    // staging geometry: tile = 128r x 32c bf16 = 8 segments of 1024 B (16 rows).
    // lane l writes LDS at seg*1024 + l*16 (linear, HW-fixed). Its datum is
    // (row = seg*16 + (l>>2), slot = l&3); source slot pre-swizzled so that
    // stored slot = src_slot ^ ((row>>1)&3).
    const int srow = lane >> 2;                              // row within segment
    const int scol = ((lane & 3) ^ ((lane >> 3) & 3)) * 8;   // swizzled src col (elems)

    const int nK = DIM / 32;   // 16

#define STAGE(bb, kk)                                                                      \
    {                                                                                      \
        const int k0 = (kk) * 32;                                                          \
        _Pragma("unroll")                                                                  \
        for (int p = 0; p < 2; p++) {                                                      \
            const int s   = wave * 2 + p;                                                  \
            const int row = s * 16 + srow;                                                 \
            const __hip_bfloat16* ga = xn + (rowBaseA + row) * DIM + k0 + scol;            \
            const __hip_bfloat16* gb = xn + (rowBaseB + row) * DIM + k0 + scol;            \
            __builtin_amdgcn_global_load_lds((const __attribute__((address_space(1))) void*)ga, \
                                             (__attribute__((address_space(3))) void*)(&lds_a[bb][s * 512]), \
                                             16, 0, 0);                                    \
            __builtin_amdgcn_global_load_lds((const __attribute__((address_space(1))) void*)gb, \
                                             (__attribute__((address_space(3))) void*)(&lds_b[bb][s * 512]), \
                                             16, 0, 0);                                    \
        }                                                                                  \
    }

    STAGE(0, 0);
    __syncthreads();   // drains vmcnt(0) then barriers

    const int rsl = (lhi ^ ((llo >> 1) & 3)) * 16;   // swizzled read byte-slot in 64B row

    for (int kk = 0; kk < nK; kk++) {
        const int cur = kk & 1;
        if (kk + 1 < nK) STAGE(cur ^ 1, kk + 1);     // issue next tile early

        bf16x8 af[4], bfr[4];
#pragma unroll
        for (int mi = 0; mi < 4; mi++) {
            const int ra = wr * 64 + mi * 16 + llo;
            const int rb = wc * 64 + mi * 16 + llo;
            af[mi]  = *(const bf16x8*)((const char*)lds_a[cur] + ra * 64 + rsl);
            bfr[mi] = *(const bf16x8*)((const char*)lds_b[cur] + rb * 64 + rsl);
        }
#pragma unroll
        for (int mi = 0; mi < 4; mi++)
#pragma unroll
            for (int ni = 0; ni < 4; ni++)
                acc[mi][ni] = __builtin_amdgcn_mfma_f32_16x16x32_bf16(af[mi], bfr[ni], acc[mi][ni], 0, 0, 0);

        __syncthreads();   // waits own vmcnt(0) + barrier: next buffer ready, cur free
    }
#undef STAGE

    // stage per-row/col metadata for the epilogue
    if (t < 128) {
        const int gi = b * NPT + tm * 128 + t;
        s_sqr[t]   = sq[gi];
        s_mr[t]    = mask[gi];
        s_cr[t][0] = coords[(size_t)gi * 3 + 0];
        s_cr[t][1] = coords[(size_t)gi * 3 + 1];
        s_cr[t][2] = coords[(size_t)gi * 3 + 2];
    } else {
        const int r  = t - 128;
        const int gi = b * NPT + tn * 128 + r;
        s_sqc[r]   = sq[gi];
        s_mc[r]    = mask[gi];
        s_cc[r][0] = coords[(size_t)gi * 3 + 0];
        s_cc[r][1] = coords[(size_t)gi * 3 + 1];
        s_cc[r][2] = coords[(size_t)gi * 3 + 2];
    }
    __syncthreads();

    // C/D layout: col = lane&15, row = (lane>>4)*4 + reg
    float lsum = 0.f;
#pragma unroll
    for (int mi = 0; mi < 4; mi++) {
#pragma unroll
        for (int j = 0; j < 4; j++) {
            const int rl  = wr * 64 + mi * 16 + lhi * 4 + j;
            const float sqr = s_sqr[rl];
            const float mr  = s_mr[rl];
            const float cx = s_cr[rl][0], cy = s_cr[rl][1], cz = s_cr[rl][2];
#pragma unroll
            for (int ni = 0; ni < 4; ni++) {
                const int cl = wc * 64 + ni * 16 + llo;
                const float g  = acc[mi][ni][j];
                float d2 = sqr + s_sqc[cl] - 2.f * g;
                d2 = fmaxf(d2, 0.f);
                const float de = sqrtf(d2);
                const float lo = fmaxf(de - 1.0f, 0.f);
                const float dx = cx - s_cc[cl][0];
                const float dy = cy - s_cc[cl][1];
                const float dz = cz - s_cc[cl][2];
                const float cd2 = dx*dx + dy*dy + dz*dz;
                const float wgt = (cd2 < 100.0f) ? mr * s_mc[cl] : 0.f;
                lsum += lo * wgt;
            }
        }
    }
    // off-diagonal tiles account for both (tm,tn) and (tn,tm): exact by symmetry
    if (tm != tn) lsum *= 2.0f;

#pragma unroll
    for (int o = 32; o; o >>= 1) lsum += __shfl_xor(lsum, o);
    if (lane == 0) s_wsum[wave] = lsum;
    __syncthreads();
    if (t == 0) {
        partials[b * NTRI + blockIdx.x] = s_wsum[0] + s_wsum[1] + s_wsum[2] + s_wsum[3];
    }
}

// ---------------- kernel 4: final deterministic reduce ----------------
__global__ __launch_bounds__(256) void finalize_kernel(const float* __restrict__ partials,
                                                       const float* __restrict__ msum,
                                                       float* __restrict__ out) {
    double s = 0.0;
    for (int i = threadIdx.x; i < BATCH * NTRI; i += 256) s += (double)partials[i];
#pragma unroll
    for (int o = 32; o; o >>= 1) s += __shfl_xor(s, o);
    __shared__ double ws[4];
    if ((threadIdx.x & 63) == 0) ws[threadIdx.x >> 6] = s;
    __syncthreads();
    if (threadIdx.x == 0) {
        const double tot = ws[0] + ws[1] + ws[2] + ws[3];
        double valid = 0.0;
        for (int b = 0; b < BATCH; b++) valid += (double)msum[b] * (double)msum[b];
        out[0] = (float)(tot / (valid + 1e-8));
    }
}

extern "C" void kernel_launch(void* const* d_in, const int* in_sizes, int n_in,
                              void* d_out, int out_size, void* d_ws, size_t ws_size,
                              hipStream_t stream) {
    const float* emb    = (const float*)d_in[0];
    const float* coords = (const float*)d_in[1];
    const float* mask   = (const float*)d_in[2];

    char* ws = (char*)d_ws;
    __hip_bfloat16* xn = (__hip_bfloat16*)ws;
    float* sq          = (float*)(ws + OFF_SQ);
    float* msum        = (float*)(ws + OFF_MSUM);
    float* partials    = (float*)(ws + OFF_PARTIALS);
    float* out         = (float*)d_out;

    normalize_kernel<<<dim3(BATCH * NPT / 4), dim3(256), 0, stream>>>(emb, xn, sq);
    masksum_kernel<<<dim3(BATCH), dim3(256), 0, stream>>>(mask, msum);
    gram_loss_kernel<<<dim3(NTRI, 1, BATCH), dim3(256), 0, stream>>>(xn, sq, coords, mask, partials);
    finalize_kernel<<<dim3(1), dim3(256), 0, stream>>>(partials, msum, out);
}